// Round 5
// baseline (411.888 us; speedup 1.0000x reference)
//
#include <hip/hip_runtime.h>
#include <hip/hip_bf16.h>

// LSTM_single_task: B=32768, I=H=512. Live math: 3 gate GEMMs (i,c,o) over
// u=[x,h] (K=1024), fused activations. f-gate and c_prev are dead code.
//
// R7: 8-phase counted-vmcnt gemm (T3+T4), derived from the 256^2 template's
// invariants. Ledger: 2-phase ceiling confirmed at 786-805 TF across R3
// (single-buf 128), R5 (dbuf prefetch 131), R6 (reg-staged fp32 A: 202,
// REVERTED - drain+cvt on critical path + 4x L2 A-traffic). This kernel:
//  - 512 thr / 8 waves (2m x 4n), BM=128, per-gate BN=128, 3 gates/block
//    (fused epilogue stays in-register), BK=64, grid 1024 (%8==0).
//  - LDS 128 KB: A[2buf][2khalf][128][32], B[2buf][2khalf][3][128][32].
//  - Phase = (K-half, m-half): B k-half fully read after its 1st phase,
//    A k-half after 2 -> half-tile slots retire cleanly; stage stream is
//    1 half-tile/phase, 3 half-tiles in flight, vmcnt(7) at ph4/ph8 ONLY
//    (7 = loads of the 3 newest half-tiles: A=1, B=3 per thread). Every
//    stage-issue is barrier-separated from the last read of its slot
//    (full slot-interval audit in comments below).
//  - 4-slot XOR swizzle slot = chunk ^ ((row>>1)&3): 2-way conflicts (free),
//    pre-swizzled global source + swizzled ds_read (both-sides rule).
//  - prep: R5's proven fused pack_weights + pack_u (U = bf16 [x|h]).

typedef unsigned short u16;
typedef u16 u16x8 __attribute__((ext_vector_type(8)));
typedef __bf16 bf16x8 __attribute__((ext_vector_type(8)));
typedef float f32x4 __attribute__((ext_vector_type(4)));

#define B_DIM 32768
#define H_DIM 512
#define K_DIM 1024
#define BH_ELEMS (B_DIM * H_DIM)          // 16,777,216
#define U_ELEMS ((long)B_DIM * K_DIM)     // 33,554,432
#define WT_BYTES ((size_t)(3u * 512u * 1024u * 2u)) // 3,145,728
#define U_BYTES ((size_t)U_ELEMS * 2u)    // 67,108,864

#define GLOBAL_AS(p) ((__attribute__((address_space(1))) void*)(p))
#define LDS_AS(p)    ((__attribute__((address_space(3))) void*)(p))

__device__ __forceinline__ float bf2f(u16 u) {
    unsigned v = ((unsigned)u) << 16;
    float f;
    __builtin_memcpy(&f, &v, 4);
    return f;
}

__device__ __forceinline__ u16 f2bf16u(float f) {
    __hip_bfloat16 b = __float2bfloat16(f);   // RNE
    u16 u;
    __builtin_memcpy(&u, &b, 2);
    return u;
}

__device__ __forceinline__ float fast_rcp(float x) {
    return __builtin_amdgcn_rcpf(x);
}

__device__ __forceinline__ float fast_sigmoid(float x) {
    return fast_rcp(1.0f + __expf(-x));
}

__device__ __forceinline__ float fast_tanh(float x) {
    float e = __expf(-2.0f * fabsf(x));
    float r = (1.0f - e) * fast_rcp(1.0f + e);
    return x < 0.0f ? -r : r;
}

// Wave-uniform dtype classification from x's first 64 words.
__device__ __forceinline__ bool derive_isbf(const unsigned* __restrict__ x, int tid) {
    const unsigned lo = x[tid & 63] & 0xFFFFu;
    const unsigned e = (lo >> 7) & 0xFFu;
    const bool sane = (e >= 100u && e <= 140u) || (lo == 0u);
    return __popcll(__ballot(sane)) >= 48;
}

// direct global->LDS, 16 B/lane; LDS dest = wave-uniform base + lane*16
__device__ __forceinline__ void gload16(const u16* g, u16* l) {
    __builtin_amdgcn_global_load_lds(GLOBAL_AS((u16*)g), LDS_AS(l), 16, 0, 0);
}

// -------- prep: pack_weights (blocks 0..1535) + pack_u (blocks 1536..5631) --
__global__ __launch_bounds__(256) void prep(
    const void* __restrict__ x, const void* __restrict__ h,
    const void* __restrict__ Wxi, const void* __restrict__ Whi,
    const void* __restrict__ Wxc, const void* __restrict__ Whc,
    const void* __restrict__ Wxo, const void* __restrict__ Who,
    u16* __restrict__ Wt, u16* __restrict__ U)
{
    __shared__ u16 tile[32][33];
    const int tid = threadIdx.x;
    const bool isbf = derive_isbf((const unsigned*)x, tid);
    const int bid = blockIdx.x;

    if (bid < 1536) {
        const int bz = bid >> 8, rem = bid & 255;
        const int by = rem >> 4, bx = rem & 15;
        const int g = bz >> 1, half = bz & 1;
        const void* src;
        if (g == 0)      src = half ? Whi : Wxi;
        else if (g == 1) src = half ? Whc : Wxc;
        else             src = half ? Who : Wxo;
        const int kk = by * 32, nn = bx * 32;
        const int tx = tid & 31, ty = tid >> 5;
        if (isbf) {
            const u16* s = (const u16*)src;
#pragma unroll
            for (int i2 = 0; i2 < 4; ++i2)
                tile[ty + 8 * i2][tx] = s[(kk + ty + 8 * i2) * 512 + nn + tx];
        } else {
            const float* s = (const float*)src;
#pragma unroll
            for (int i2 = 0; i2 < 4; ++i2)
                tile[ty + 8 * i2][tx] = f2bf16u(s[(kk + ty + 8 * i2) * 512 + nn + tx]);
        }
        __syncthreads();
#pragma unroll
        for (int i2 = 0; i2 < 4; ++i2)
            Wt[(long)g * 524288 + (long)(nn + ty + 8 * i2) * 1024 + half * 512 + kk + tx]
                = tile[tx][ty + 8 * i2];
    } else {
        const long stride = 4096L * 256L;
        for (long t = (long)(bid - 1536) * 256 + tid;
             t < (U_ELEMS >> 3); t += stride) {
            const long e = t << 3;
            const int r = (int)(e >> 10);
            const int k = (int)(e & 1023);
            const void* src = (k < 512) ? x : h;
            const long so = (long)r * 512 + (k & 511);
            u16x8 o;
            if (isbf) {
                o = *(const u16x8*)((const u16*)src + so);
            } else {
                const float* s = (const float*)src + so;
                f32x4 p0 = *(const f32x4*)s;
                f32x4 p1 = *(const f32x4*)(s + 4);
#pragma unroll
                for (int j = 0; j < 4; ++j) {
                    o[j] = f2bf16u(p0[j]);
                    o[4 + j] = f2bf16u(p1[j]);
                }
            }
            *(u16x8*)(U + e) = o;
        }
    }
}

// -------- main v5: 8-phase counted-vmcnt GEMM -----------------------------
// Slot audit (iter t computes kt0=2t in buf0 ph1-4, kt1=2t+1 in buf1 ph5-8;
// stage stream: ph1:(2t+1).A1  ph2:(2t+2).B0  ph3:(2t+2).A0  ph4:(2t+2).B1
//               ph5:(2t+2).A1  ph6:(2t+3).B0  ph7:(2t+3).A0  ph8:(2t+3).B1):
//   buf0.B.k0 read ph1            -> overwritten by issue at ph2   (1 bar)
//   buf0.A.k0 read ph1,ph2        -> ph3; buf0.B.k1 read ph3 -> ph4
//   buf0.A.k1 read ph3,ph4        -> ph5; buf1.B.k0 read ph5 -> ph6
//   buf1.A.k0 read ph5,ph6        -> ph7; buf1.B.k1 read ph7 -> ph8
//   buf1.A.k1 read ph7,ph8        -> ph1 of next iter
// Landing guarantees: vmcnt(7)@ph4 leaves newest {ph4.B1,ph3.A0,ph2.B0}=7
// outstanding -> ph1's A1 (read ph7) landed; vmcnt(7)@ph8 leaves
// {ph8.B1,ph7.A0,ph6.B0} -> ph5's A1 + everything older landed, covering
// next iter's ph1/ph3 reads. Prologue ends in the identical in-flight state.
__global__ __launch_bounds__(512, 1) void lstm_gemm_v5(
    const void* __restrict__ x,                   // only for dtype probe
    const u16* __restrict__ U, const u16* __restrict__ Wt,
    const void* __restrict__ bxi, const void* __restrict__ bxc,
    const void* __restrict__ bxo, void* __restrict__ out)
{
    __shared__ __align__(16) u16 Al[4 * 4096];    // [buf*2+kh][128][4*8]  32 KB
    __shared__ __align__(16) u16 Bl[4 * 12288];   // [buf*2+kh][3][128][4*8] 96 KB

    const int tid  = threadIdx.x;
    const bool isbf = derive_isbf((const unsigned*)x, tid);
    const int lane = tid & 63;
    const int wave = tid >> 6;          // 0..7
    const int wave_m = wave >> 2;       // 0..1  (64-row half)
    const int wave_n = wave & 3;        // 0..3  (32-col quarter)

    // XCD-chunked swizzle: 1024 blocks, xcd = bid&7 owns 32 m-panels x 4 n.
    const int bid = blockIdx.x;
    const int xcd = bid & 7, ii = bid >> 3;
    const int m0 = (xcd * 32 + (ii >> 2)) * 128;
    const int n0 = (ii & 3) * 128;      // within-gate col base

    // ---- staging addressing (pre-swizzled global source) ------------------
    // thread t covers row tid>>2, dest slot tid&3 within a khalf block;
    // slot c at row r must hold global chunk c ^ ((r>>1)&3).
    const int arow = tid >> 2;          // 0..127
    const int asrc = (((tid & 3) ^ ((arow >> 1) & 3))) * 8;  // u16 in khalf
    const long a_base = (long)(m0 + arow) * 1024 + asrc;
    long b_base[3];
#pragma unroll
    for (int g = 0; g < 3; ++g)
        b_base[g] = (long)(g * 512 + n0 + arow) * 1024 + asrc;

    // ---- reader offsets (u16 index within a khalf block) ------------------
    // frag: row = base + (lane&15), chunk = lane>>4, slot = chunk^((row>>1)&3)
    int arof[4];
#pragma unroll
    for (int mr = 0; mr < 4; ++mr) {
        const int row = wave_m * 64 + mr * 16 + (lane & 15);
        const int slot = (lane >> 4) ^ ((row >> 1) & 3);
        arof[mr] = row * 32 + slot * 8;
    }
    int brof[3][2];
#pragma unroll
    for (int g = 0; g < 3; ++g)
#pragma unroll
        for (int nr = 0; nr < 2; ++nr) {
            const int row = wave_n * 32 + nr * 16 + (lane & 15);
            const int slot = (lane >> 4) ^ ((row >> 1) & 3);
            brof[g][nr] = g * 4096 + row * 32 + slot * 8;
        }

    f32x4 acc[3][4][2];
    const f32x4 zero = {0.f, 0.f, 0.f, 0.f};
#pragma unroll
    for (int g = 0; g < 3; ++g)
#pragma unroll
        for (int mr = 0; mr < 4; ++mr)
#pragma unroll
            for (int nr = 0; nr < 2; ++nr)
                acc[g][mr][nr] = zero;

    bf16x8 bfr[3][2];                   // B frags persist across the m-half pair

#define SA(BUF, KH, KOFF) \
    gload16(U + a_base + (KOFF) + (KH) * 32, &Al[((BUF) * 2 + (KH)) * 4096 + wave * 512])
#define SB(BUF, KH, KOFF) do {                                                \
    _Pragma("unroll")                                                         \
    for (int g_ = 0; g_ < 3; ++g_)                                            \
        gload16(Wt + b_base[g_] + (KOFF) + (KH) * 32,                         \
                &Bl[((BUF) * 2 + (KH)) * 12288 + g_ * 4096 + wave * 512]);    \
} while (0)
#define NOSTAGE ((void)0)
#define VMW(N) asm volatile("s_waitcnt vmcnt(" #N ")" ::: "memory")
#define BAR() __builtin_amdgcn_s_barrier()

#define PH(BUF, KK, MH, STAGE) do {                                           \
    bf16x8 af0 = *(const bf16x8*)&Al[((BUF)*2+(KK))*4096 + arof[(MH)*2+0]];   \
    bf16x8 af1 = *(const bf16x8*)&Al[((BUF)*2+(KK))*4096 + arof[(MH)*2+1]];   \
    if ((MH) == 0) {                                                          \
        _Pragma("unroll")                                                     \
        for (int g_ = 0; g_ < 3; ++g_)                                        \
            _Pragma("unroll")                                                 \
            for (int nr_ = 0; nr_ < 2; ++nr_)                                 \
                bfr[g_][nr_] = *(const bf16x8*)&Bl[((BUF)*2+(KK))*12288 + brof[g_][nr_]]; \
    }                                                                         \
    STAGE;                                                                    \
    BAR();                                                                    \
    asm volatile("s_waitcnt lgkmcnt(0)" ::: "memory");                        \
    __builtin_amdgcn_sched_barrier(0);                                        \
    __builtin_amdgcn_s_setprio(1);                                            \
    _Pragma("unroll")                                                         \
    for (int g_ = 0; g_ < 3; ++g_)                                            \
        _Pragma("unroll")                                                     \
        for (int nr_ = 0; nr_ < 2; ++nr_) {                                   \
            acc[g_][(MH)*2+0][nr_] = __builtin_amdgcn_mfma_f32_16x16x32_bf16( \
                af0, bfr[g_][nr_], acc[g_][(MH)*2+0][nr_], 0, 0, 0);          \
            acc[g_][(MH)*2+1][nr_] = __builtin_amdgcn_mfma_f32_16x16x32_bf16( \
                af1, bfr[g_][nr_], acc[g_][(MH)*2+1][nr_], 0, 0, 0);          \
        }                                                                     \
    __builtin_amdgcn_s_setprio(0);                                            \
} while (0)

    // ---- prologue: kt0 fully staged, kt1 {B0,A0,B1} in flight (7 loads) ---
    SA(0, 0, 0); SA(0, 1, 0); SB(0, 0, 0); SB(0, 1, 0);   // kt0 (8 loads)
    SB(1, 0, 64); SA(1, 0, 64); SB(1, 1, 64);             // kt1 (7 loads)
    VMW(7);                                               // kt0 landed
    BAR();

    // ---- steady iters t = 0..6 (compute kt 2t,2t+1; stage 2t+2,2t+3) ------
    for (int t = 0; t < 7; ++t) {
        const int kb = t * 128;
        PH(0, 0, 0, SA(1, 1, kb + 64));            BAR();
        PH(0, 0, 1, SB(0, 0, kb + 128));           BAR();
        PH(0, 1, 0, SA(0, 0, kb + 128));           BAR();
        PH(0, 1, 1, SB(0, 1, kb + 128)); VMW(7);   BAR();
        PH(1, 0, 0, SA(0, 1, kb + 128));           BAR();
        PH(1, 0, 1, SB(1, 0, kb + 192));           BAR();
        PH(1, 1, 0, SA(1, 0, kb + 192));           BAR();
        PH(1, 1, 1, SB(1, 1, kb + 192)); VMW(7);   BAR();
    }
    // ---- final iter (kt14, kt15): only kt15.A1 still to stage -------------
    PH(0, 0, 0, SA(1, 1, 960));  BAR();
    PH(0, 0, 1, NOSTAGE);        BAR();
    PH(0, 1, 0, NOSTAGE);        BAR();
    PH(0, 1, 1, NOSTAGE); VMW(0); BAR();           // drain: kt15 fully landed
    PH(1, 0, 0, NOSTAGE);        BAR();
    PH(1, 0, 1, NOSTAGE);        BAR();
    PH(1, 1, 0, NOSTAGE);        BAR();
    PH(1, 1, 1, NOSTAGE);

#undef SA
#undef SB
#undef NOSTAGE
#undef VMW
#undef BAR
#undef PH

    // ---- epilogue: bias + activations + store (dtype-matched) -------------
    // C/D layout: col = lane&15, row = (lane>>4)*4 + reg  [m89/m91 verified]
    const int colbase = n0 + wave_n * 32 + (lane & 15);
    float bi[2], bc[2], bo[2];
#pragma unroll
    for (int nr = 0; nr < 2; ++nr) {
        const int col = colbase + nr * 16;
        if (isbf) {
            bi[nr] = bf2f(((const u16*)bxi)[col]);
            bc[nr] = bf2f(((const u16*)bxc)[col]);
            bo[nr] = bf2f(((const u16*)bxo)[col]);
        } else {
            bi[nr] = ((const float*)bxi)[col];
            bc[nr] = ((const float*)bxc)[col];
            bo[nr] = ((const float*)bxo)[col];
        }
    }

    const int rowbase = m0 + wave_m * 64 + (lane >> 4) * 4;
#pragma unroll
    for (int mr = 0; mr < 4; ++mr)
#pragma unroll
        for (int nr = 0; nr < 2; ++nr)
#pragma unroll
            for (int r = 0; r < 4; ++r) {
                const int row = rowbase + mr * 16 + r;
                const int col = colbase + nr * 16;
                const float iv = fast_sigmoid(acc[0][mr][nr][r] + bi[nr]);
                const float cv = iv * fast_tanh(acc[1][mr][nr][r] + bc[nr]);
                const float ov = fast_sigmoid(acc[2][mr][nr][r] + bo[nr]);
                const float hv = ov * fast_tanh(cv);
                const long idx = (long)row * 512 + col;
                if (isbf) {
                    ((u16*)out)[idx]            = f2bf16u(hv);
                    ((u16*)out)[BH_ELEMS + idx] = f2bf16u(cv);
                } else {
                    ((float*)out)[idx]            = hv;
                    ((float*)out)[BH_ELEMS + idx] = cv;
                }
            }
}

// -------- fallback (R2-style): used only if ws can't hold Wt + U ----------
__global__ __launch_bounds__(256, 2) void lstm_gemm_fb(
    const void* __restrict__ x, const void* __restrict__ h,
    const u16* __restrict__ Wt,
    const void* __restrict__ bxi, const void* __restrict__ bxc,
    const void* __restrict__ bxo, void* __restrict__ out)
{
    __shared__ __align__(16) u16 As[128 * 32];
    __shared__ __align__(16) u16 Bs[3 * 64 * 32];

    const int tid    = threadIdx.x;
    const bool isbf  = derive_isbf((const unsigned*)x, tid);
    const int lane   = tid & 63;
    const int wave   = tid >> 6;
    const int wave_m = wave & 1;
    const int wave_n = wave >> 1;
    const int m0 = blockIdx.y * 128;
    const int n0 = blockIdx.x * 64;

    const int trow = tid >> 2, tkc = (tid & 3) * 8;
    const long a_g0 = (long)(m0 + trow)      * 512 + tkc;
    const long a_g1 = (long)(m0 + 64 + trow) * 512 + tkc;
    const int  a_l0 = tid * 8;
    const int  a_l1 = 2048 + tid * 8;
    long b_g[3];
#pragma unroll
    for (int q = 0; q < 3; ++q)
        b_g[q] = (long)q * 524288 + (long)(n0 + trow) * 1024 + tkc;

    int a_ld[4];
#pragma unroll
    for (int mt = 0; mt < 4; ++mt)
        a_ld[mt] = (wave_m * 64 + mt * 16 + (lane & 15)) * 32 + (lane >> 4) * 8;
    int b_ld[3][2];
#pragma unroll
    for (int g = 0; g < 3; ++g)
#pragma unroll
        for (int nt = 0; nt < 2; ++nt)
            b_ld[g][nt] = g * 2048 + (wave_n * 32 + nt * 16 + (lane & 15)) * 32 + (lane >> 4) * 8;

    f32x4 acc[3][4][2];
    const f32x4 zero = {0.f, 0.f, 0.f, 0.f};
#pragma unroll
    for (int g = 0; g < 3; ++g)
#pragma unroll
        for (int mt = 0; mt < 4; ++mt)
#pragma unroll
            for (int nt = 0; nt < 2; ++nt)
                acc[g][mt][nt] = zero;

    for (int k0 = 0; k0 < K_DIM; k0 += 32) {
        const void* src = (k0 < 512) ? x : h;
        const long kadj = (k0 < 512) ? k0 : (k0 - 512);

        bf16x8 av0, av1, bv[3];
        if (isbf) {
            const u16* s = (const u16*)src + kadj;
            u16x8 t0 = *(const u16x8*)(s + a_g0);
            u16x8 t1 = *(const u16x8*)(s + a_g1);
            __builtin_memcpy(&av0, &t0, 16);
            __builtin_memcpy(&av1, &t1, 16);
        } else {
            const float* s = (const float*)src + kadj;
            f32x4 p0 = *(const f32x4*)(s + a_g0);
            f32x4 p1 = *(const f32x4*)(s + a_g0 + 4);
            f32x4 q0 = *(const f32x4*)(s + a_g1);
            f32x4 q1 = *(const f32x4*)(s + a_g1 + 4);
#pragma unroll
            for (int j = 0; j < 4; ++j) {
                av0[j] = (__bf16)p0[j]; av0[4 + j] = (__bf16)p1[j];
                av1[j] = (__bf16)q0[j]; av1[4 + j] = (__bf16)q1[j];
            }
        }
#pragma unroll
        for (int q = 0; q < 3; ++q) {
            u16x8 t = *(const u16x8*)(Wt + b_g[q] + k0);
            __builtin_memcpy(&bv[q], &t, 16);
        }

        __syncthreads();
        *(bf16x8*)&As[a_l0] = av0;
        *(bf16x8*)&As[a_l1] = av1;
#pragma unroll
        for (int q = 0; q < 3; ++q)
            *(bf16x8*)&Bs[q * 2048 + tid * 8] = bv[q];
        __syncthreads();

        bf16x8 af[4];
#pragma unroll
        for (int mt = 0; mt < 4; ++mt)
            af[mt] = *(const bf16x8*)&As[a_ld[mt]];
        bf16x8 bfr[3][2];
#pragma unroll
        for (int g = 0; g < 3; ++g)
#pragma unroll
            for (int nt = 0; nt < 2; ++nt)
                bfr[g][nt] = *(const bf16x8*)&Bs[b_ld[g][nt]];

#pragma unroll
        for (int g = 0; g < 3; ++g)
#pragma unroll
            for (int mt = 0; mt < 4; ++mt)
#pragma unroll
            for (int nt = 0; nt < 2; ++nt)
                acc[g][mt][nt] = __builtin_amdgcn_mfma_f32_16x16x32_bf16(
                    af[mt], bfr[g][nt], acc[g][mt][nt], 0, 0, 0);
    }

    const int colbase = n0 + wave_n * 32 + (lane & 15);
    float bi[2], bc[2], bo[2];
#pragma unroll
    for (int nt = 0; nt < 2; ++nt) {
        const int col = colbase + nt * 16;
        if (isbf) {
            bi[nt] = bf2f(((const u16*)bxi)[col]);
            bc[nt] = bf2f(((const u16*)bxc)[col]);
            bo[nt] = bf2f(((const u16*)bxo)[col]);
        } else {
            bi[nt] = ((const float*)bxi)[col];
            bc[nt] = ((const float*)bxc)[col];
            bo[nt] = ((const float*)bxo)[col];
        }
    }

    const int rowbase = m0 + wave_m * 64 + (lane >> 4) * 4;
#pragma unroll
    for (int mt = 0; mt < 4; ++mt)
#pragma unroll
        for (int nt = 0; nt < 2; ++nt)
#pragma unroll
            for (int r = 0; r < 4; ++r) {
                const int row = rowbase + mt * 16 + r;
                const int col = colbase + nt * 16;
                const float iv = fast_sigmoid(acc[0][mt][nt][r] + bi[nt]);
                const float cv = iv * fast_tanh(acc[1][mt][nt][r] + bc[nt]);
                const float ov = fast_sigmoid(acc[2][mt][nt][r] + bo[nt]);
                const float hv = ov * fast_tanh(cv);
                const long idx = (long)row * 512 + col;
                if (isbf) {
                    ((u16*)out)[idx]            = f2bf16u(hv);
                    ((u16*)out)[BH_ELEMS + idx] = f2bf16u(cv);
                } else {
                    ((float*)out)[idx]            = hv;
                    ((float*)out)[BH_ELEMS + idx] = cv;
                }
            }
}

extern "C" void kernel_launch(void* const* d_in, const int* in_sizes, int n_in,
                              void* d_out, int out_size, void* d_ws, size_t ws_size,
                              hipStream_t stream) {
    const void* x   = d_in[0];
    const void* h   = d_in[1];
    // d_in[2] = c_prev: dead in reference math, not read.
    const void* Wxi = d_in[3];
    const void* bxi = d_in[4];
    const void* Whi = d_in[5];
    // d_in[6..8] = Wxf/bxf/Whf: f gate is computed-then-discarded -> skipped.
    const void* Wxc = d_in[9];
    const void* bxc = d_in[10];
    const void* Whc = d_in[11];
    const void* Wxo = d_in[12];
    const void* bxo = d_in[13];
    const void* Who = d_in[14];

    u16* Wt = (u16*)d_ws;                         // 3 MB packed weights (bf16)
    const size_t need = WT_BYTES + U_BYTES;       // ~70.3 MB

    if (ws_size >= need) {
        u16* U = (u16*)((char*)d_ws + WT_BYTES);  // 64 MB bf16 [x|h]
        prep<<<dim3(1536 + 4096), dim3(256), 0, stream>>>(
            x, h, Wxi, Whi, Wxc, Whc, Wxo, Who, Wt, U);
        lstm_gemm_v5<<<dim3(1024), dim3(512), 0, stream>>>(
            x, U, Wt, bxi, bxc, bxo, d_out);
    } else {
        prep<<<dim3(1536), dim3(256), 0, stream>>>(     // pack_weights only
            x, h, Wxi, Whi, Wxc, Whc, Wxo, Who, Wt, nullptr);
        lstm_gemm_fb<<<dim3(8, 256), dim3(256), 0, stream>>>(
            x, h, Wt, bxi, bxc, bxo, d_out);
    }
}